// Round 1
// baseline (3197.887 us; speedup 1.0000x reference)
//
#include <hip/hip_runtime.h>
#include <hip/hip_bf16.h>
#include <cstddef>

// Problem constants (fixed by reference)
#define N_USERS   100000
#define N_ITEMS   100000
#define N_NODES   200000
#define D         64
#define BATCH     2048
#define HIST      50

// ---------------- init: x0 = concat(user_emb, item_emb[1:]); acc = x0 ----------------
__global__ void k_init(const float* __restrict__ user_emb, const float* __restrict__ item_emb,
                       float* __restrict__ x, float* __restrict__ acc) {
    int f = blockIdx.x * 256 + threadIdx.x;              // float4 index
    if (f >= N_NODES * (D / 4)) return;
    int row = f >> 4, c4 = f & 15;
    const float4* src = (row < N_USERS)
        ? ((const float4*)user_emb) + (size_t)row * 16 + c4
        : ((const float4*)item_emb) + (size_t)(row - (N_USERS - 1)) * 16 + c4;  // row-100000+1
    float4 v = *src;
    ((float4*)x)[f] = v;
    ((float4*)acc)[f] = v;
}

// ---------------- CSR build ----------------
__global__ void k_hist(const int* __restrict__ adj_row, int* __restrict__ deg, int nedges) {
    int e = blockIdx.x * 256 + threadIdx.x;
    if (e < nedges) atomicAdd(&deg[adj_row[e]], 1);
}

__global__ __launch_bounds__(256) void k_scan_block(const int* __restrict__ deg,
                                                    int* __restrict__ rowptr, int* __restrict__ bsums) {
    __shared__ int s[256];
    int t = threadIdx.x;
    int base = blockIdx.x * 1024 + t * 4;
    int d[4]; int tsum = 0;
#pragma unroll
    for (int k = 0; k < 4; ++k) { d[k] = (base + k < N_NODES) ? deg[base + k] : 0; tsum += d[k]; }
    s[t] = tsum; __syncthreads();
    for (int off = 1; off < 256; off <<= 1) {
        int v = (t >= off) ? s[t - off] : 0;
        __syncthreads();
        s[t] += v;
        __syncthreads();
    }
    int excl = s[t] - tsum;
    int run = excl;
#pragma unroll
    for (int k = 0; k < 4; ++k) { if (base + k < N_NODES) rowptr[base + k] = run; run += d[k]; }
    if (t == 255) bsums[blockIdx.x] = s[255];
}

__global__ __launch_bounds__(256) void k_scan_sums(int* __restrict__ bsums, int nb) {
    __shared__ int s[256];
    int t = threadIdx.x;
    int v0 = (t < nb) ? bsums[t] : 0;
    s[t] = v0; __syncthreads();
    for (int off = 1; off < 256; off <<= 1) {
        int v = (t >= off) ? s[t - off] : 0;
        __syncthreads();
        s[t] += v;
        __syncthreads();
    }
    if (t < nb) bsums[t] = s[t] - v0;   // exclusive
}

__global__ void k_scan_add(int* __restrict__ rowptr, const int* __restrict__ bsums, int nedges) {
    int i = blockIdx.x * 256 + threadIdx.x;
    if (i < N_NODES) rowptr[i] += bsums[i >> 10];
    if (i == 0) rowptr[N_NODES] = nedges;
}

__global__ void k_scatter(const int* __restrict__ adj_row, const int* __restrict__ adj_col,
                          const float* __restrict__ adj_val, const int* __restrict__ rowptr,
                          int* __restrict__ cursor, int2* __restrict__ edges, int nedges) {
    int e = blockIdx.x * 256 + threadIdx.x;
    if (e >= nedges) return;
    int r = adj_row[e];
    int p = rowptr[r] + atomicAdd(&cursor[r], 1);
    int2 ev; ev.x = adj_col[e]; ev.y = __float_as_int(adj_val[e]);
    edges[p] = ev;
}

// ---------------- propagate: one wave per row, lane = dim; fused acc += ----------------
__global__ __launch_bounds__(256) void k_prop(const int* __restrict__ rowptr, const int2* __restrict__ edges,
                                              const float* __restrict__ x_in, float* __restrict__ x_out,
                                              float* __restrict__ acc) {
    int w = blockIdx.x * 4 + (threadIdx.x >> 6);
    int lane = threadIdx.x & 63;
    if (w >= N_NODES) return;
    int s = rowptr[w], e = rowptr[w + 1];
    float sum = 0.f;
    for (int p = s; p < e; ++p) {
        int2 ev = edges[p];
        sum += __int_as_float(ev.y) * x_in[(size_t)ev.x * D + lane];
    }
    x_out[(size_t)w * D + lane] = sum;
    acc[(size_t)w * D + lane] += sum;
}

// ---------------- pred + label score: one wave per batch row, lane = dim ----------------
__global__ __launch_bounds__(256) void k_pred(const int* __restrict__ user_seqs, const int* __restrict__ his,
                                              const int* __restrict__ next_items,
                                              const float* __restrict__ item_emb, const float* __restrict__ acc,
                                              float* __restrict__ pred, float* __restrict__ slabel) {
    int b = blockIdx.x * 4 + (threadIdx.x >> 6);
    int lane = threadIdx.x & 63;
    int u = user_seqs[b];
    float sum = 0.f; int cnt = 0;
    for (int j = 0; j < HIST; ++j) {
        int it = his[b * HIST + j];
        cnt += (it != 0);
        sum += item_emb[(size_t)it * D + lane];   // item_emb[0] is all-zero (pad)
    }
    float pv = acc[(size_t)u * D + lane] * 0.25f + sum / (float)cnt;
    pred[(size_t)b * D + lane] = pv;
    int lab = next_items[b] - 1;
    float tv = pv * (acc[(size_t)(N_USERS + lab) * D + lane] * 0.25f);
#pragma unroll
    for (int off = 32; off > 0; off >>= 1) tv += __shfl_down(tv, off);
    if (lane == 0) slabel[b] = tv;
}

// ---------------- scores + max-free sumexp ----------------
// grid = (ceil(N_ITEMS/256), BATCH/512); thread = one item (64 regs), loops 512 batch rows
__global__ __launch_bounds__(256) void k_scores(const float* __restrict__ acc, const float* __restrict__ pred,
                                                float* __restrict__ sumexp) {
    __shared__ float wsum[512][4];
    int t = threadIdx.x, wv = t >> 6, lane = t & 63;
    int item = blockIdx.x * 256 + t;
    bool valid = item < N_ITEMS;
    int it = valid ? item : 0;
    const float4* src = (const float4*)(acc + (size_t)(N_USERS + it) * D);
    float ir[64];
#pragma unroll
    for (int d4 = 0; d4 < 16; ++d4) {
        float4 v = src[d4];
        ir[4 * d4 + 0] = v.x * 0.25f; ir[4 * d4 + 1] = v.y * 0.25f;
        ir[4 * d4 + 2] = v.z * 0.25f; ir[4 * d4 + 3] = v.w * 0.25f;
    }
    int bbase = blockIdx.y * 512;
    for (int rb = 0; rb < 512; ++rb) {
        const float4* pr = (const float4*)(pred + (size_t)(bbase + rb) * D);
        float s = 0.f;
#pragma unroll
        for (int d4 = 0; d4 < 16; ++d4) {
            float4 p = pr[d4];
            s += ir[4 * d4 + 0] * p.x + ir[4 * d4 + 1] * p.y
               + ir[4 * d4 + 2] * p.z + ir[4 * d4 + 3] * p.w;
        }
        float e = valid ? __expf(s) : 0.f;   // scores are O(1): max-free sumexp is safe in fp32
#pragma unroll
        for (int off = 32; off > 0; off >>= 1) e += __shfl_down(e, off);
        if (lane == 0) wsum[rb][wv] = e;
    }
    __syncthreads();
    for (int rb = t; rb < 512; rb += 256) {
        float tot = wsum[rb][0] + wsum[rb][1] + wsum[rb][2] + wsum[rb][3];
        unsafeAtomicAdd(&sumexp[bbase + rb], tot);
    }
}

// ---------------- final loss reduce ----------------
__global__ __launch_bounds__(256) void k_loss(const float* __restrict__ sumexp, const float* __restrict__ slabel,
                                              float* __restrict__ out) {
    __shared__ float ws[4];
    int t = threadIdx.x;
    float v = 0.f;
    for (int i = t; i < BATCH; i += 256) v += __logf(sumexp[i]) - slabel[i];
#pragma unroll
    for (int off = 32; off > 0; off >>= 1) v += __shfl_down(v, off);
    if ((t & 63) == 0) ws[t >> 6] = v;
    __syncthreads();
    if (t == 0) out[0] = (ws[0] + ws[1] + ws[2] + ws[3]) * (1.f / (float)BATCH);
}

extern "C" void kernel_launch(void* const* d_in, const int* in_sizes, int n_in,
                              void* d_out, int out_size, void* d_ws, size_t ws_size,
                              hipStream_t stream) {
    const int*   user_seqs = (const int*)d_in[0];
    const int*   his       = (const int*)d_in[1];
    const int*   next_itm  = (const int*)d_in[2];
    const int*   adj_row   = (const int*)d_in[3];
    const int*   adj_col   = (const int*)d_in[4];
    const float* adj_val   = (const float*)d_in[5];
    const float* user_emb  = (const float*)d_in[6];
    const float* item_emb  = (const float*)d_in[7];
    float* out = (float*)d_out;
    int nedges = in_sizes[3];   // 6,400,000

    // Workspace layout (fp32/int32 words). Total ~208 MB.
    float* ws      = (float*)d_ws;
    float* acc     = ws;                       // 12,800,000
    float* x_a     = acc + (size_t)N_NODES * D;    // 12,800,000
    float* x_b     = x_a + (size_t)N_NODES * D;    // 12,800,000
    float* pred    = x_b + (size_t)N_NODES * D;    // 131,072
    float* slabel  = pred + BATCH * D;             // 2,048
    float* sumexp  = slabel + BATCH;               // 2,048   (zeroed)
    int*   deg     = (int*)(sumexp + BATCH);       // 200,000 (zeroed)
    int*   cursor  = deg + N_NODES;                // 200,000 (zeroed)
    int*   rowptr  = cursor + N_NODES;             // 200,002 (padded even)
    int*   bsums   = rowptr + (N_NODES + 2);       // 256
    int2*  edges   = (int2*)(bsums + 256);         // 6,400,000 int2 (8B-aligned)

    // zero sumexp + deg + cursor in one shot (contiguous)
    hipMemsetAsync(sumexp, 0, (size_t)(BATCH + 2 * N_NODES) * sizeof(int), stream);

    k_init<<<(N_NODES * (D / 4) + 255) / 256, 256, 0, stream>>>(user_emb, item_emb, x_a, acc);

    k_hist<<<(nedges + 255) / 256, 256, 0, stream>>>(adj_row, deg, nedges);
    int nsb = (N_NODES + 1023) / 1024;  // 196
    k_scan_block<<<nsb, 256, 0, stream>>>(deg, rowptr, bsums);
    k_scan_sums<<<1, 256, 0, stream>>>(bsums, nsb);
    k_scan_add<<<(N_NODES + 255) / 256, 256, 0, stream>>>(rowptr, bsums, nedges);
    k_scatter<<<(nedges + 255) / 256, 256, 0, stream>>>(adj_row, adj_col, adj_val, rowptr, cursor, edges, nedges);

    k_prop<<<N_NODES / 4, 256, 0, stream>>>(rowptr, edges, x_a, x_b, acc);
    k_prop<<<N_NODES / 4, 256, 0, stream>>>(rowptr, edges, x_b, x_a, acc);
    k_prop<<<N_NODES / 4, 256, 0, stream>>>(rowptr, edges, x_a, x_b, acc);

    k_pred<<<BATCH / 4, 256, 0, stream>>>(user_seqs, his, next_itm, item_emb, acc, pred, slabel);

    dim3 gs((N_ITEMS + 255) / 256, BATCH / 512);
    k_scores<<<gs, 256, 0, stream>>>(acc, pred, sumexp);

    k_loss<<<1, 256, 0, stream>>>(sumexp, slabel, out);
}

// Round 3
// 3036.511 us; speedup vs baseline: 1.0531x; 1.0531x over previous
//
#include <hip/hip_runtime.h>
#include <hip/hip_bf16.h>
#include <cstddef>

// Problem constants (fixed by reference)
#define N_USERS   100000
#define N_ITEMS   100000
#define N_NODES   200000
#define D         64
#define BATCH     2048
#define HIST      50
#define N_ITEMS_PAD 100096   // padded to multiple of 128 (block item-chunk)

typedef __attribute__((ext_vector_type(8))) short short8;
typedef __attribute__((ext_vector_type(16))) float float16;

__device__ __forceinline__ ushort f2bf(float x) {  // fp32 -> bf16 RNE
    unsigned u = __float_as_uint(x);
    return (ushort)((u + 0x7FFF + ((u >> 16) & 1)) >> 16);
}

// ---------------- init: x0 = concat(user_emb, item_emb[1:]); acc = x0 ----------------
__global__ void k_init(const float* __restrict__ user_emb, const float* __restrict__ item_emb,
                       float* __restrict__ x, float* __restrict__ acc) {
    int f = blockIdx.x * 256 + threadIdx.x;              // float4 index
    if (f >= N_NODES * (D / 4)) return;
    int row = f >> 4, c4 = f & 15;
    const float4* src = (row < N_USERS)
        ? ((const float4*)user_emb) + (size_t)row * 16 + c4
        : ((const float4*)item_emb) + (size_t)(row - (N_USERS - 1)) * 16 + c4;  // row-100000+1
    float4 v = *src;
    ((float4*)x)[f] = v;
    ((float4*)acc)[f] = v;
}

// ---------------- CSR build ----------------
__global__ void k_hist(const int* __restrict__ adj_row, int* __restrict__ deg, int nedges) {
    int e = blockIdx.x * 256 + threadIdx.x;
    if (e < nedges) atomicAdd(&deg[adj_row[e]], 1);
}

__global__ __launch_bounds__(256) void k_scan_block(const int* __restrict__ deg,
                                                    int* __restrict__ rowptr, int* __restrict__ bsums) {
    __shared__ int s[256];
    int t = threadIdx.x;
    int base = blockIdx.x * 1024 + t * 4;
    int d[4]; int tsum = 0;
#pragma unroll
    for (int k = 0; k < 4; ++k) { d[k] = (base + k < N_NODES) ? deg[base + k] : 0; tsum += d[k]; }
    s[t] = tsum; __syncthreads();
    for (int off = 1; off < 256; off <<= 1) {
        int v = (t >= off) ? s[t - off] : 0;
        __syncthreads();
        s[t] += v;
        __syncthreads();
    }
    int excl = s[t] - tsum;
    int run = excl;
#pragma unroll
    for (int k = 0; k < 4; ++k) { if (base + k < N_NODES) rowptr[base + k] = run; run += d[k]; }
    if (t == 255) bsums[blockIdx.x] = s[255];
}

__global__ __launch_bounds__(256) void k_scan_sums(int* __restrict__ bsums, int nb) {
    __shared__ int s[256];
    int t = threadIdx.x;
    int v0 = (t < nb) ? bsums[t] : 0;
    s[t] = v0; __syncthreads();
    for (int off = 1; off < 256; off <<= 1) {
        int v = (t >= off) ? s[t - off] : 0;
        __syncthreads();
        s[t] += v;
        __syncthreads();
    }
    if (t < nb) bsums[t] = s[t] - v0;   // exclusive
}

__global__ void k_scan_add(int* __restrict__ rowptr, const int* __restrict__ bsums, int nedges) {
    int i = blockIdx.x * 256 + threadIdx.x;
    if (i < N_NODES) rowptr[i] += bsums[i >> 10];
    if (i == 0) rowptr[N_NODES] = nedges;
}

__global__ void k_scatter(const int* __restrict__ adj_row, const int* __restrict__ adj_col,
                          const float* __restrict__ adj_val, const int* __restrict__ rowptr,
                          int* __restrict__ cursor, int2* __restrict__ edges, int nedges) {
    int e = blockIdx.x * 256 + threadIdx.x;
    if (e >= nedges) return;
    int r = adj_row[e];
    int p = rowptr[r] + atomicAdd(&cursor[r], 1);
    int2 ev; ev.x = adj_col[e]; ev.y = __float_as_int(adj_val[e]);
    edges[p] = ev;
}

// ---------------- propagate: one wave per row, lane = dim; fused acc += ----------------
__global__ __launch_bounds__(256) void k_prop(const int* __restrict__ rowptr, const long long* __restrict__ edges,
                                              const float* __restrict__ x_in, float* __restrict__ x_out,
                                              float* __restrict__ acc) {
    int w = blockIdx.x * 4 + (threadIdx.x >> 6);
    int lane = threadIdx.x & 63;
    if (w >= N_NODES) return;
    int s = rowptr[w], e = rowptr[w + 1];
    float sum = 0.f;
    for (int p = s; p < e; ++p) {
        long long ev = __builtin_nontemporal_load(&edges[p]);   // streaming; keep L2 for x gathers
        int col = (int)(ev & 0xFFFFFFFFll);
        float v = __int_as_float((int)(ev >> 32));
        sum += v * x_in[(size_t)col * D + lane];
    }
    x_out[(size_t)w * D + lane] = sum;
    acc[(size_t)w * D + lane] += sum;
}

// ---------------- convert item latents to bf16 (scaled by 1/4), zero-pad to 100096 ----------------
__global__ void k_conv_items(const float* __restrict__ acc, ushort* __restrict__ item_bf) {
    int f = blockIdx.x * 256 + threadIdx.x;    // one ushort4 (4 elems) per thread
    if (f >= N_ITEMS_PAD * (D / 4)) return;
    int row = f >> 4;
    ushort4 o;
    if (row < N_ITEMS) {
        float4 v = ((const float4*)(acc + (size_t)(N_USERS + row) * D))[f & 15];
        o.x = f2bf(v.x * 0.25f); o.y = f2bf(v.y * 0.25f);
        o.z = f2bf(v.z * 0.25f); o.w = f2bf(v.w * 0.25f);
    } else {
        o.x = o.y = o.z = o.w = 0;   // pad rows -> score exactly 0 -> exp = 1 (subtract 96 in k_loss)
    }
    ((ushort4*)item_bf)[f] = o;
}

// ---------------- pred (bf16 copy) + label score ----------------
__global__ __launch_bounds__(256) void k_pred(const int* __restrict__ user_seqs, const int* __restrict__ his,
                                              const int* __restrict__ next_items,
                                              const float* __restrict__ item_emb, const float* __restrict__ acc,
                                              ushort* __restrict__ pred_bf, float* __restrict__ slabel) {
    int b = blockIdx.x * 4 + (threadIdx.x >> 6);
    int lane = threadIdx.x & 63;
    int u = user_seqs[b];
    float sum = 0.f; int cnt = 0;
    for (int j = 0; j < HIST; ++j) {
        int it = his[b * HIST + j];
        cnt += (it != 0);
        sum += item_emb[(size_t)it * D + lane];   // item_emb[0] is all-zero (pad)
    }
    float pv = acc[(size_t)u * D + lane] * 0.25f + sum / (float)cnt;
    pred_bf[(size_t)b * D + lane] = f2bf(pv);
    int lab = next_items[b] - 1;
    float tv = pv * (acc[(size_t)(N_USERS + lab) * D + lane] * 0.25f);
#pragma unroll
    for (int off = 32; off > 0; off >>= 1) tv += __shfl_down(tv, off);
    if (lane == 0) slabel[b] = tv;
}

// ---------------- MFMA scores + max-free sumexp ----------------
// D[item][batch] = item_bf(32xK) x pred_bf^T(Kx32) per wave; block = 4 waves = 128 items.
// A-frags (items) loaded once; loop 64 batch tiles of 32; epilogue exp + row-sum into
// per-wave LDS (no conflicts, no atomics); one global atomic per m per block at the end.
__global__ __launch_bounds__(256) void k_scores(const ushort* __restrict__ item_bf,
                                                const ushort* __restrict__ pred_bf,
                                                float* __restrict__ sumexp) {
    __shared__ float lds[4 * 2048];  // 4 waves x 2048 floats = 32 KB
    int t = threadIdx.x, wv = t >> 6, lane = t & 63;
    for (int i = t; i < 4 * 2048; i += 256) lds[i] = 0.f;
    __syncthreads();

    int item0 = blockIdx.x * 128 + wv * 32 + (lane & 31);
    int khalf = (lane >> 5) * 8;   // which 8-elem k-half this lane holds

    const ushort* ib = item_bf + (size_t)item0 * D + khalf;
    short8 afrag[4];
#pragma unroll
    for (int tt = 0; tt < 4; ++tt) afrag[tt] = *(const short8*)(ib + 16 * tt);

    float* myld = lds + wv * 2048;
    for (int mi = 0; mi < 64; ++mi) {
        int mtile = mi * 32;
        const ushort* pb = pred_bf + (size_t)(mtile + (lane & 31)) * D + khalf;
        short8 b0 = *(const short8*)(pb);
        short8 b1 = *(const short8*)(pb + 16);
        short8 b2 = *(const short8*)(pb + 32);
        short8 b3 = *(const short8*)(pb + 48);
        float16 c = {0.f};
        c = __builtin_amdgcn_mfma_f32_32x32x16_bf16(afrag[0], b0, c, 0, 0, 0);
        c = __builtin_amdgcn_mfma_f32_32x32x16_bf16(afrag[1], b1, c, 0, 0, 0);
        c = __builtin_amdgcn_mfma_f32_32x32x16_bf16(afrag[2], b2, c, 0, 0, 0);
        c = __builtin_amdgcn_mfma_f32_32x32x16_bf16(afrag[3], b3, c, 0, 0, 0);
        float part = 0.f;
#pragma unroll
        for (int r = 0; r < 16; ++r) part += __expf(c[r]);
        part += __shfl_down(part, 32);          // fold the two col-duplicate half-waves
        if (lane < 32) {
            float* p = myld + mtile + lane;     // wave-private, conflict-free
            *p += part;
        }
    }
    __syncthreads();
    for (int m = t; m < 2048; m += 256) {
        float v = lds[m] + lds[2048 + m] + lds[4096 + m] + lds[6144 + m];
        unsafeAtomicAdd(&sumexp[m], v);
    }
}

// ---------------- final loss reduce ----------------
__global__ __launch_bounds__(256) void k_loss(const float* __restrict__ sumexp, const float* __restrict__ slabel,
                                              float* __restrict__ out) {
    __shared__ float ws[4];
    int t = threadIdx.x;
    float v = 0.f;
    for (int i = t; i < BATCH; i += 256)
        v += __logf(sumexp[i] - 96.0f) - slabel[i];   // -96: padded items contribute exp(0)=1 each
#pragma unroll
    for (int off = 32; off > 0; off >>= 1) v += __shfl_down(v, off);
    if ((t & 63) == 0) ws[t >> 6] = v;
    __syncthreads();
    if (t == 0) out[0] = (ws[0] + ws[1] + ws[2] + ws[3]) * (1.f / (float)BATCH);
}

extern "C" void kernel_launch(void* const* d_in, const int* in_sizes, int n_in,
                              void* d_out, int out_size, void* d_ws, size_t ws_size,
                              hipStream_t stream) {
    const int*   user_seqs = (const int*)d_in[0];
    const int*   his       = (const int*)d_in[1];
    const int*   next_itm  = (const int*)d_in[2];
    const int*   adj_row   = (const int*)d_in[3];
    const int*   adj_col   = (const int*)d_in[4];
    const float* adj_val   = (const float*)d_in[5];
    const float* user_emb  = (const float*)d_in[6];
    const float* item_emb  = (const float*)d_in[7];
    float* out = (float*)d_out;
    int nedges = in_sizes[3];   // 6,400,000

    // Workspace layout (fp32/int32 words). ~208 MB, same as R0.
    float* ws      = (float*)d_ws;
    float* acc     = ws;                           // 12,800,000 f
    float* x_a     = acc + (size_t)N_NODES * D;    // 12,800,000 f
    float* x_b     = x_a + (size_t)N_NODES * D;    // 12,800,000 f
    float* slabel  = x_b + (size_t)N_NODES * D;    // 2,048
    float* sumexp  = slabel + BATCH;               // 2,048   (zeroed)
    int*   deg     = (int*)(sumexp + BATCH);       // 200,000 (zeroed)
    int*   cursor  = deg + N_NODES;                // 200,000 (zeroed)
    int*   rowptr  = cursor + N_NODES;             // 200,002
    int*   bsums   = rowptr + (N_NODES + 2);       // 256
    int2*  edges   = (int2*)(bsums + 256);         // 6,400,000 int2

    // bf16 buffers overlay x_a, which is dead after the 3rd k_prop (reads x_a, writes x_b)
    ushort* item_bf = (ushort*)x_a;                          // 100096*64 ushorts (12.8 MB)
    ushort* pred_bf = item_bf + (size_t)N_ITEMS_PAD * D;     // 131072 ushorts

    // zero sumexp + deg + cursor in one shot (contiguous)
    hipError_t _e = hipMemsetAsync(sumexp, 0, (size_t)(BATCH + 2 * N_NODES) * sizeof(int), stream);
    (void)_e;

    k_init<<<(N_NODES * (D / 4) + 255) / 256, 256, 0, stream>>>(user_emb, item_emb, x_a, acc);

    k_hist<<<(nedges + 255) / 256, 256, 0, stream>>>(adj_row, deg, nedges);
    int nsb = (N_NODES + 1023) / 1024;  // 196
    k_scan_block<<<nsb, 256, 0, stream>>>(deg, rowptr, bsums);
    k_scan_sums<<<1, 256, 0, stream>>>(bsums, nsb);
    k_scan_add<<<(N_NODES + 255) / 256, 256, 0, stream>>>(rowptr, bsums, nedges);
    k_scatter<<<(nedges + 255) / 256, 256, 0, stream>>>(adj_row, adj_col, adj_val, rowptr, cursor, edges, nedges);

    k_prop<<<N_NODES / 4, 256, 0, stream>>>(rowptr, (const long long*)edges, x_a, x_b, acc);
    k_prop<<<N_NODES / 4, 256, 0, stream>>>(rowptr, (const long long*)edges, x_b, x_a, acc);
    k_prop<<<N_NODES / 4, 256, 0, stream>>>(rowptr, (const long long*)edges, x_a, x_b, acc);
    // x_a now dead -> overlay bf16 buffers

    k_conv_items<<<(N_ITEMS_PAD * (D / 4) + 255) / 256, 256, 0, stream>>>(acc, item_bf);
    k_pred<<<BATCH / 4, 256, 0, stream>>>(user_seqs, his, next_itm, item_emb, acc, pred_bf, slabel);

    k_scores<<<N_ITEMS_PAD / 128, 256, 0, stream>>>(item_bf, pred_bf, sumexp);

    k_loss<<<1, 256, 0, stream>>>(sumexp, slabel, out);
}

// Round 4
// 1402.614 us; speedup vs baseline: 2.2799x; 2.1649x over previous
//
#include <hip/hip_runtime.h>
#include <hip/hip_bf16.h>
#include <cstddef>

// Problem constants (fixed by reference)
#define N_USERS   100000
#define N_ITEMS   100000
#define N_NODES   200000
#define D         64
#define BATCH     2048
#define HIST      50
#define N_ITEMS_PAD 100096   // padded to multiple of 128 (block item-chunk)

typedef __attribute__((ext_vector_type(8))) short short8;
typedef __attribute__((ext_vector_type(16))) float float16;

__device__ __forceinline__ ushort f2bf(float x) {  // fp32 -> bf16 RNE
    unsigned u = __float_as_uint(x);
    return (ushort)((u + 0x7FFF + ((u >> 16) & 1)) >> 16);
}
__device__ __forceinline__ float bfu(ushort u) {   // bf16 -> fp32
    return __uint_as_float(((unsigned)u) << 16);
}

// ---------------- init: x_bf0 = bf16(concat(user_emb, item_emb[1:])) ----------------
__global__ void k_init(const float* __restrict__ user_emb, const float* __restrict__ item_emb,
                       ushort* __restrict__ xbf0) {
    int f = blockIdx.x * 256 + threadIdx.x;              // one ushort4 (4 dims)
    if (f >= N_NODES * (D / 4)) return;
    int row = f >> 4;
    const float4* src = (row < N_USERS)
        ? ((const float4*)user_emb) + (size_t)row * 16 + (f & 15)
        : ((const float4*)item_emb) + (size_t)(row - (N_USERS - 1)) * 16 + (f & 15);
    float4 v = *src;
    ushort4 o; o.x = f2bf(v.x); o.y = f2bf(v.y); o.z = f2bf(v.z); o.w = f2bf(v.w);
    ((ushort4*)xbf0)[f] = o;
}

// ---------------- CSR build ----------------
__global__ void k_hist(const int* __restrict__ adj_row, int* __restrict__ deg, int nedges) {
    int e = blockIdx.x * 256 + threadIdx.x;
    if (e < nedges) atomicAdd(&deg[adj_row[e]], 1);
}

__global__ __launch_bounds__(256) void k_scan_block(const int* __restrict__ deg,
                                                    int* __restrict__ rowptr, int* __restrict__ bsums) {
    __shared__ int s[256];
    int t = threadIdx.x;
    int base = blockIdx.x * 1024 + t * 4;
    int d[4]; int tsum = 0;
#pragma unroll
    for (int k = 0; k < 4; ++k) { d[k] = (base + k < N_NODES) ? deg[base + k] : 0; tsum += d[k]; }
    s[t] = tsum; __syncthreads();
    for (int off = 1; off < 256; off <<= 1) {
        int v = (t >= off) ? s[t - off] : 0;
        __syncthreads();
        s[t] += v;
        __syncthreads();
    }
    int excl = s[t] - tsum;
    int run = excl;
#pragma unroll
    for (int k = 0; k < 4; ++k) { if (base + k < N_NODES) rowptr[base + k] = run; run += d[k]; }
    if (t == 255) bsums[blockIdx.x] = s[255];
}

__global__ __launch_bounds__(256) void k_scan_sums(int* __restrict__ bsums, int nb) {
    __shared__ int s[256];
    int t = threadIdx.x;
    int v0 = (t < nb) ? bsums[t] : 0;
    s[t] = v0; __syncthreads();
    for (int off = 1; off < 256; off <<= 1) {
        int v = (t >= off) ? s[t - off] : 0;
        __syncthreads();
        s[t] += v;
        __syncthreads();
    }
    if (t < nb) bsums[t] = s[t] - v0;   // exclusive
}

__global__ void k_scan_add(int* __restrict__ rowptr, const int* __restrict__ bsums, int nedges) {
    int i = blockIdx.x * 256 + threadIdx.x;
    if (i < N_NODES) rowptr[i] += bsums[i >> 10];
    if (i == 0) rowptr[N_NODES] = nedges;
}

__global__ void k_scatter(const int* __restrict__ adj_row, const int* __restrict__ adj_col,
                          const float* __restrict__ adj_val, const int* __restrict__ rowptr,
                          int* __restrict__ cursor, int2* __restrict__ edges, int nedges) {
    int e = blockIdx.x * 256 + threadIdx.x;
    if (e >= nedges) return;
    int r = adj_row[e];
    int p = rowptr[r] + atomicAdd(&cursor[r], 1);
    int2 ev; ev.x = adj_col[e]; ev.y = __float_as_int(adj_val[e]);
    edges[p] = ev;
}

// ---------------- propagate (bf16): one wave per row, lane = dim; 8x unrolled gather ----------------
__global__ __launch_bounds__(256) void k_prop(const int* __restrict__ rowptr, const long long* __restrict__ edges,
                                              const ushort* __restrict__ x_in, ushort* __restrict__ x_out) {
    int w = blockIdx.x * 4 + (threadIdx.x >> 6);
    int lane = threadIdx.x & 63;
    if (w >= N_NODES) return;
    int s = rowptr[w], e = rowptr[w + 1];
    float sum = 0.f;
    int p = s;
    for (; p + 8 <= e; p += 8) {
        long long ev[8];
#pragma unroll
        for (int j = 0; j < 8; ++j) ev[j] = edges[p + j];
        float xv[8], vv[8];
#pragma unroll
        for (int j = 0; j < 8; ++j) {
            int col = (int)(ev[j] & 0xFFFFFFFFll);
            vv[j] = __int_as_float((int)(ev[j] >> 32));
            xv[j] = bfu(x_in[(size_t)col * D + lane]);
        }
#pragma unroll
        for (int j = 0; j < 8; ++j) sum += vv[j] * xv[j];
    }
    for (; p < e; ++p) {
        long long ev = edges[p];
        int col = (int)(ev & 0xFFFFFFFFll);
        float v = __int_as_float((int)(ev >> 32));
        sum += v * bfu(x_in[(size_t)col * D + lane]);
    }
    x_out[(size_t)w * D + lane] = f2bf(sum);
}

// ---------------- item latents: 0.25*(item_emb + x1+x2+x3) -> bf16, zero-pad ----------------
__global__ void k_conv_items(const float* __restrict__ item_emb,
                             const ushort* __restrict__ x1, const ushort* __restrict__ x2,
                             const ushort* __restrict__ x3, ushort* __restrict__ item_bf) {
    int f = blockIdx.x * 256 + threadIdx.x;    // one ushort4 (4 dims)
    if (f >= N_ITEMS_PAD * (D / 4)) return;
    int row = f >> 4, c4 = f & 15;
    ushort4 o;
    if (row < N_ITEMS) {
        size_t nrow = (size_t)(N_USERS + row) * 16 + c4;   // in ushort4 units
        float4 e4 = ((const float4*)(item_emb + (size_t)(row + 1) * D))[c4];
        ushort4 a = ((const ushort4*)x1)[nrow];
        ushort4 b = ((const ushort4*)x2)[nrow];
        ushort4 c = ((const ushort4*)x3)[nrow];
        o.x = f2bf(0.25f * (e4.x + bfu(a.x) + bfu(b.x) + bfu(c.x)));
        o.y = f2bf(0.25f * (e4.y + bfu(a.y) + bfu(b.y) + bfu(c.y)));
        o.z = f2bf(0.25f * (e4.z + bfu(a.z) + bfu(b.z) + bfu(c.z)));
        o.w = f2bf(0.25f * (e4.w + bfu(a.w) + bfu(b.w) + bfu(c.w)));
    } else {
        o.x = o.y = o.z = o.w = 0;   // pad rows -> score 0 -> exp = 1 (subtract 96 in k_loss)
    }
    ((ushort4*)item_bf)[f] = o;
}

// ---------------- pred (bf16 copy) + label score ----------------
__global__ __launch_bounds__(256) void k_pred(const int* __restrict__ user_seqs, const int* __restrict__ his,
                                              const int* __restrict__ next_items,
                                              const float* __restrict__ user_emb, const float* __restrict__ item_emb,
                                              const ushort* __restrict__ x1, const ushort* __restrict__ x2,
                                              const ushort* __restrict__ x3,
                                              ushort* __restrict__ pred_bf, float* __restrict__ slabel) {
    int b = blockIdx.x * 4 + (threadIdx.x >> 6);
    int lane = threadIdx.x & 63;
    int u = user_seqs[b];
    float sum = 0.f; int cnt = 0;
    for (int j = 0; j < HIST; ++j) {
        int it = his[b * HIST + j];
        cnt += (it != 0);
        sum += item_emb[(size_t)it * D + lane];   // item_emb[0] is all-zero (pad)
    }
    size_t ur = (size_t)u * D + lane;
    float ulat = 0.25f * (user_emb[ur] + bfu(x1[ur]) + bfu(x2[ur]) + bfu(x3[ur]));
    float pv = ulat + sum / (float)cnt;
    pred_bf[(size_t)b * D + lane] = f2bf(pv);
    int lab = next_items[b] - 1;
    size_t nr = (size_t)(N_USERS + lab) * D + lane;
    float ilat = 0.25f * (item_emb[(size_t)(lab + 1) * D + lane] + bfu(x1[nr]) + bfu(x2[nr]) + bfu(x3[nr]));
    float tv = pv * ilat;
#pragma unroll
    for (int off = 32; off > 0; off >>= 1) tv += __shfl_down(tv, off);
    if (lane == 0) slabel[b] = tv;
}

// ---------------- MFMA scores + max-free sumexp ----------------
__global__ __launch_bounds__(256) void k_scores(const ushort* __restrict__ item_bf,
                                                const ushort* __restrict__ pred_bf,
                                                float* __restrict__ sumexp) {
    __shared__ float lds[4 * 2048];  // 4 waves x 2048 floats = 32 KB
    int t = threadIdx.x, wv = t >> 6, lane = t & 63;
    for (int i = t; i < 4 * 2048; i += 256) lds[i] = 0.f;
    __syncthreads();

    int item0 = blockIdx.x * 128 + wv * 32 + (lane & 31);
    int khalf = (lane >> 5) * 8;   // which 8-elem k-half this lane holds

    const ushort* ib = item_bf + (size_t)item0 * D + khalf;
    short8 afrag[4];
#pragma unroll
    for (int tt = 0; tt < 4; ++tt) afrag[tt] = *(const short8*)(ib + 16 * tt);

    float* myld = lds + wv * 2048;
    for (int mi = 0; mi < 64; ++mi) {
        int mtile = mi * 32;
        const ushort* pb = pred_bf + (size_t)(mtile + (lane & 31)) * D + khalf;
        short8 b0 = *(const short8*)(pb);
        short8 b1 = *(const short8*)(pb + 16);
        short8 b2 = *(const short8*)(pb + 32);
        short8 b3 = *(const short8*)(pb + 48);
        float16 c = {0.f};
        c = __builtin_amdgcn_mfma_f32_32x32x16_bf16(afrag[0], b0, c, 0, 0, 0);
        c = __builtin_amdgcn_mfma_f32_32x32x16_bf16(afrag[1], b1, c, 0, 0, 0);
        c = __builtin_amdgcn_mfma_f32_32x32x16_bf16(afrag[2], b2, c, 0, 0, 0);
        c = __builtin_amdgcn_mfma_f32_32x32x16_bf16(afrag[3], b3, c, 0, 0, 0);
        float part = 0.f;
#pragma unroll
        for (int r = 0; r < 16; ++r) part += __expf(c[r]);
        part += __shfl_down(part, 32);          // fold the two col-duplicate half-waves
        if (lane < 32) {
            float* p = myld + mtile + lane;     // wave-private, conflict-free
            *p += part;
        }
    }
    __syncthreads();
    for (int m = t; m < 2048; m += 256) {
        float v = lds[m] + lds[2048 + m] + lds[4096 + m] + lds[6144 + m];
        unsafeAtomicAdd(&sumexp[m], v);
    }
}

// ---------------- final loss reduce ----------------
__global__ __launch_bounds__(256) void k_loss(const float* __restrict__ sumexp, const float* __restrict__ slabel,
                                              float* __restrict__ out) {
    __shared__ float ws[4];
    int t = threadIdx.x;
    float v = 0.f;
    for (int i = t; i < BATCH; i += 256)
        v += __logf(sumexp[i] - 96.0f) - slabel[i];   // -96: padded items contribute exp(0)=1 each
#pragma unroll
    for (int off = 32; off > 0; off >>= 1) v += __shfl_down(v, off);
    if ((t & 63) == 0) ws[t >> 6] = v;
    __syncthreads();
    if (t == 0) out[0] = (ws[0] + ws[1] + ws[2] + ws[3]) * (1.f / (float)BATCH);
}

extern "C" void kernel_launch(void* const* d_in, const int* in_sizes, int n_in,
                              void* d_out, int out_size, void* d_ws, size_t ws_size,
                              hipStream_t stream) {
    const int*   user_seqs = (const int*)d_in[0];
    const int*   his       = (const int*)d_in[1];
    const int*   next_itm  = (const int*)d_in[2];
    const int*   adj_row   = (const int*)d_in[3];
    const int*   adj_col   = (const int*)d_in[4];
    const float* adj_val   = (const float*)d_in[5];
    const float* user_emb  = (const float*)d_in[6];
    const float* item_emb  = (const float*)d_in[7];
    float* out = (float*)d_out;
    int nedges = in_sizes[3];   // 12,800,000

    // Workspace layout (~220 MB; harness provided >=256 MB in prior rounds)
    ushort* xbf0   = (ushort*)d_ws;                        // 12.8M ushort (25.6 MB)
    ushort* xbf1   = xbf0 + (size_t)N_NODES * D;
    ushort* xbf2   = xbf1 + (size_t)N_NODES * D;
    ushort* xbf3   = xbf2 + (size_t)N_NODES * D;
    float*  slabel = (float*)(xbf3 + (size_t)N_NODES * D); // 2,048
    float*  sumexp = slabel + BATCH;                       // 2,048   (zeroed)
    int*    deg    = (int*)(sumexp + BATCH);               // 200,000 (zeroed)
    int*    cursor = deg + N_NODES;                        // 200,000 (zeroed)
    int*    rowptr = cursor + N_NODES;                     // 200,002
    int*    bsums  = rowptr + (N_NODES + 2);               // 256
    int2*   edges  = (int2*)(bsums + 256);                 // 12.8M int2 (102.4 MB)
    ushort* item_bf = (ushort*)(edges + (size_t)nedges);   // 100096*64 ushort
    ushort* pred_bf = item_bf + (size_t)N_ITEMS_PAD * D;   // 131072 ushort

    // zero sumexp + deg + cursor in one shot (contiguous)
    hipError_t _e = hipMemsetAsync(sumexp, 0, (size_t)(BATCH + 2 * N_NODES) * sizeof(int), stream);
    (void)_e;

    k_init<<<(N_NODES * (D / 4) + 255) / 256, 256, 0, stream>>>(user_emb, item_emb, xbf0);

    k_hist<<<(nedges + 255) / 256, 256, 0, stream>>>(adj_row, deg, nedges);
    int nsb = (N_NODES + 1023) / 1024;  // 196
    k_scan_block<<<nsb, 256, 0, stream>>>(deg, rowptr, bsums);
    k_scan_sums<<<1, 256, 0, stream>>>(bsums, nsb);
    k_scan_add<<<(N_NODES + 255) / 256, 256, 0, stream>>>(rowptr, bsums, nedges);
    k_scatter<<<(nedges + 255) / 256, 256, 0, stream>>>(adj_row, adj_col, adj_val, rowptr, cursor, edges, nedges);

    k_prop<<<N_NODES / 4, 256, 0, stream>>>(rowptr, (const long long*)edges, xbf0, xbf1);
    k_prop<<<N_NODES / 4, 256, 0, stream>>>(rowptr, (const long long*)edges, xbf1, xbf2);
    k_prop<<<N_NODES / 4, 256, 0, stream>>>(rowptr, (const long long*)edges, xbf2, xbf3);

    k_conv_items<<<(N_ITEMS_PAD * (D / 4) + 255) / 256, 256, 0, stream>>>(item_emb, xbf1, xbf2, xbf3, item_bf);
    k_pred<<<BATCH / 4, 256, 0, stream>>>(user_seqs, his, next_itm, user_emb, item_emb,
                                          xbf1, xbf2, xbf3, pred_bf, slabel);

    k_scores<<<N_ITEMS_PAD / 128, 256, 0, stream>>>(item_bf, pred_bf, sumexp);

    k_loss<<<1, 256, 0, stream>>>(sumexp, slabel, out);
}